// Round 8
// baseline (174.369 us; speedup 1.0000x reference)
//
#include <hip/hip_runtime.h>
#include <math.h>

#define BB 4
#define CC 128
#define HW 4096
// sqrt(10 * log2(e)) — folds 1/tau AND exp->exp2 into both normalized sides:
// sim' = sim * log2(e), so exp(sim) == exp2(sim').
#define SCF 3.798282565f

typedef short short8 __attribute__((ext_vector_type(8)));
typedef float f32x4 __attribute__((ext_vector_type(4)));

static __device__ inline unsigned short f2bf(float f) {
  // round-to-nearest-even fp32 -> bf16 (inputs are finite)
  unsigned int u = __float_as_uint(f);
  u += 0x7fffu + ((u >> 16) & 1u);
  return (unsigned short)(u >> 16);
}

static __device__ inline float fast_exp2(float x) {
#if __has_builtin(__builtin_amdgcn_exp2f)
  return __builtin_amdgcn_exp2f(x);
#else
  return exp2f(x);
#endif
}

// Fragment-major layout: for batch b, 16-position chunk t, k-slice kc, the
// 64 lanes' 16B fragments are stored contiguously:
//   addr(b,t,kc,lane) = (((b*256 + t)*4 + kc)*64 + lane) * 8 shorts
// where lane = g*16 + ml holds position t*16+ml, channels (kc*4+g)*8..+8.
// MFMA fragment loads AND LDS staging are contiguous wave-wide streams:
// no swizzle, no bank conflicts anywhere.  [verified correct in R7]

// K1: per 32-position tile: inv-norms of A and B, fp32 diagonal similarity,
// zero expsum + completion counter, write bf16 normalized*SCF features in
// fragment-major order.
__global__ __launch_bounds__(256) void k_prep(const float* __restrict__ fA,
                                              const float* __restrict__ fB,
                                              unsigned short* __restrict__ fAn,
                                              unsigned short* __restrict__ fBn,
                                              float* __restrict__ diag,
                                              float* __restrict__ expsum,
                                              float* __restrict__ acc) {
  __shared__ float sA[32 * 129];
  __shared__ float sB[32 * 129];
  __shared__ float red[3 * 256];

  const int bid = blockIdx.x;          // 0..511 : b*128 + tile
  const int b   = bid >> 7;
  const int n0  = (bid & 127) * 32;
  const int tid = threadIdx.x;
  const int cR  = tid >> 5;            // 0..7
  const int n   = tid & 31;            // 0..31

  if (bid == 0 && tid == 0) { acc[0] = 0.f; acc[1] = 0.f; ((unsigned*)acc)[2] = 0u; }

  const float* pa = fA + (size_t)b * CC * HW + n0 + n;
  const float* pb = fB + (size_t)b * CC * HW + n0 + n;

  float ssa = 0.f, ssb = 0.f, dot = 0.f;
  #pragma unroll
  for (int it = 0; it < 16; ++it) {
    int c = it * 8 + cR;
    float va = pa[(size_t)c * HW];
    float vb = pb[(size_t)c * HW];
    sA[n * 129 + c] = va;
    sB[n * 129 + c] = vb;
    ssa = fmaf(va, va, ssa);
    ssb = fmaf(vb, vb, ssb);
    dot = fmaf(va, vb, dot);
  }
  red[tid] = ssa; red[256 + tid] = ssb; red[512 + tid] = dot;
  __syncthreads();

  if (tid < 32) {
    float sa = 0.f, sb = 0.f, dt = 0.f;
    #pragma unroll
    for (int k = 0; k < 8; ++k) {
      sa += red[k * 32 + tid];
      sb += red[256 + k * 32 + tid];
      dt += red[512 + k * 32 + tid];
    }
    float ia = 1.f / fmaxf(sqrtf(sa), 1e-12f);
    float ib = 1.f / fmaxf(sqrtf(sb), 1e-12f);
    int gidx = b * HW + n0 + tid;
    diag[gidx]   = dt * ia * ib * 10.f;   // true sim scale (1/tau)
    expsum[gidx] = 0.f;
    red[tid]      = ia * SCF;   // sole reader/writer of these slots
    red[32 + tid] = ib * SCF;
  }
  __syncthreads();

  // write phase: fragment-major; tid = kc*64 + g*16 + ml
  const int ml = tid & 15;
  const int g  = (tid >> 4) & 3;
  const int kc = tid >> 6;
  #pragma unroll
  for (int r = 0; r < 2; ++r) {
    int nn = r * 16 + ml;             // row within the 32-row tile
    int c0 = (kc * 4 + g) * 8;        // channel base
    size_t base = ((((size_t)b * 256 + (n0 >> 4) + r) * 4 + kc) * 64 + (g * 16 + ml)) * 8;
    {
      float sc = red[nn];
      const float* s = &sA[nn * 129 + c0];
      uint4 v;
      v.x = f2bf(s[0]*sc) | ((unsigned)f2bf(s[1]*sc) << 16);
      v.y = f2bf(s[2]*sc) | ((unsigned)f2bf(s[3]*sc) << 16);
      v.z = f2bf(s[4]*sc) | ((unsigned)f2bf(s[5]*sc) << 16);
      v.w = f2bf(s[6]*sc) | ((unsigned)f2bf(s[7]*sc) << 16);
      *(uint4*)(fAn + base) = v;
    }
    {
      float sc = red[32 + nn];
      const float* s = &sB[nn * 129 + c0];
      uint4 v;
      v.x = f2bf(s[0]*sc) | ((unsigned)f2bf(s[1]*sc) << 16);
      v.y = f2bf(s[2]*sc) | ((unsigned)f2bf(s[3]*sc) << 16);
      v.z = f2bf(s[4]*sc) | ((unsigned)f2bf(s[5]*sc) << 16);
      v.w = f2bf(s[6]*sc) | ((unsigned)f2bf(s[7]*sc) << 16);
      *(uint4*)(fBn + base) = v;
    }
  }
}

// K2: 128x128 tile per block, 4x4 outer-product per wave (m97 geometry),
// both operands from LDS, but K is processed in TWO halves of 64 so the LDS
// footprint is 32 KB -> 3-4 blocks/CU co-resident (barrier stalls hidden by
// other blocks). Fragment-major => identity global_load_lds staging and
// conflict-free contiguous ds_read_b128 frag loads. Fused exp2 column-sum
// epilogue + last-block loss finish.
__global__ __launch_bounds__(256) void k_main(const unsigned short* __restrict__ fAn,
                                              const unsigned short* __restrict__ fBn,
                                              float* __restrict__ expsum,
                                              const float* __restrict__ diag,
                                              const float* __restrict__ mask,
                                              float* __restrict__ acc,
                                              float* __restrict__ out) {
  __shared__ unsigned short lds[16384];   // 32 KB: A-half 16 KB | B-half 16 KB
  unsigned short* ldsA = lds;
  unsigned short* ldsB = lds + 8192;
  __shared__ float redS[16];
  __shared__ unsigned flagS;

  const int bid = blockIdx.x;                 // 0..4095
  const int x   = bid & 7;                    // XCD (heuristic bid%8)
  const int b   = x & 3;
  const int nh  = x >> 2;                     // n-half pinned per XCD
  const int t   = bid >> 3;                   // 0..511
  const int nt  = nh * 16 + (t & 15);         // 0..31  (128-row A tile)
  const int mt  = t >> 4;                     // 0..31  (128-col B tile)
  const int tid = threadIdx.x;

  const int wv   = tid >> 6;
  const int lane = tid & 63;
  const int ml   = lane & 15;
  const int wn   = (wv & 1) * 4;     // wave's first A t-chunk (of 8) in tile
  const int wm   = (wv >> 1) * 4;    // wave's first B t-chunk (of 8) in tile

  // t-chunk = 4 kc * 512 shorts = 2048 shorts
  const unsigned short* gA = fAn + ((size_t)b * 256 + nt * 8) * 2048;
  const unsigned short* gB = fBn + ((size_t)b * 256 + mt * 8) * 2048;

  f32x4 acc4[4][4] = {};   // [i = A subtile][j = B subtile]

  #pragma unroll
  for (int h = 0; h < 2; ++h) {   // K-half: kc = 2h + k2
    // stage: A-half 1024 16B-chunks + B-half 1024 16B-chunks (identity-ish:
    // for fixed t, the two kc sub-blocks of this half are 2 KB contiguous)
    #pragma unroll
    for (int r = 0; r < 4; ++r) {
      int L  = r * 256 + tid;          // 0..1023
      int tt = L >> 7;                 // t-chunk 0..7
      int k2 = (L >> 6) & 1;
      int lc = L & 63;
      __builtin_amdgcn_global_load_lds(
          (const __attribute__((address_space(1))) unsigned int*)
              (gA + (((size_t)tt * 4 + 2 * h + k2) * 64 + lc) * 8),
          (__attribute__((address_space(3))) unsigned int*)
              (ldsA + ((tt * 2 + k2) * 64 + lc) * 8), 16, 0, 0);
      __builtin_amdgcn_global_load_lds(
          (const __attribute__((address_space(1))) unsigned int*)
              (gB + (((size_t)tt * 4 + 2 * h + k2) * 64 + lc) * 8),
          (__attribute__((address_space(3))) unsigned int*)
              (ldsB + ((tt * 2 + k2) * 64 + lc) * 8), 16, 0, 0);
    }
    __syncthreads();   // staging complete

    #pragma unroll
    for (int k2 = 0; k2 < 2; ++k2) {
      short8 af[4], bf[4];
      #pragma unroll
      for (int i = 0; i < 4; ++i)
        af[i] = *(const short8*)(ldsA + ((wn + i) * 2 + k2) * 512 + lane * 8);
      #pragma unroll
      for (int j = 0; j < 4; ++j)
        bf[j] = *(const short8*)(ldsB + ((wm + j) * 2 + k2) * 512 + lane * 8);
      #pragma unroll
      for (int i = 0; i < 4; ++i)
        #pragma unroll
        for (int j = 0; j < 4; ++j)
          acc4[i][j] = __builtin_amdgcn_mfma_f32_16x16x32_bf16(af[i], bf[j], acc4[i][j], 0, 0, 0);
    }
    if (h == 0) __syncthreads();   // all frag reads done before restaging
  }

  // epilogue: per-column sums of exp2(sim'). C layout: col=lane&15, row=g*4+r.
  // |sim'| <= 14.43 -> exp2 within fp32 range, no shift needed.
  #pragma unroll
  for (int j = 0; j < 4; ++j) {
    float e = 0.f;
    #pragma unroll
    for (int i = 0; i < 4; ++i)
      #pragma unroll
      for (int r = 0; r < 4; ++r)
        e += fast_exp2(acc4[i][j][r]);
    e += __shfl_xor(e, 16, 64);
    e += __shfl_xor(e, 32, 64);
    if (lane < 16)
      atomicAdd(&expsum[(size_t)b * HW + mt * 128 + (wm + j) * 16 + ml], e);
  }

  // last-block loss finish
  __syncthreads();                 // all waves' atomics issued
  if (tid == 0) {
    __threadfence();
    flagS = (atomicAdd((unsigned*)(acc + 2), 1u) == 4095u) ? 1u : 0u;
  }
  __syncthreads();
  if (flagS) {
    float num = 0.f, den = 0.f;
    #pragma unroll 4
    for (int i = tid; i < BB * HW; i += 256) {
      float es = __hip_atomic_load(expsum + i, __ATOMIC_RELAXED, __HIP_MEMORY_SCOPE_AGENT);
      float mv = mask[i];
      num = fmaf(mv, __logf(es) - diag[i], num);   // ln(sum exp(sim)) - sim_kk
      den += mv;
    }
    #pragma unroll
    for (int off = 32; off; off >>= 1) {
      num += __shfl_down(num, off, 64);
      den += __shfl_down(den, off, 64);
    }
    if (lane == 0) { redS[wv] = num; redS[8 + wv] = den; }
    __syncthreads();
    if (tid == 0) {
      float n = redS[0] + redS[1] + redS[2] + redS[3];
      float d = redS[8] + redS[9] + redS[10] + redS[11];
      out[0] = n / (d + 1e-6f);
    }
  }
}

extern "C" void kernel_launch(void* const* d_in, const int* in_sizes, int n_in,
                              void* d_out, int out_size, void* d_ws, size_t ws_size,
                              hipStream_t stream) {
  const float* feat_A = (const float*)d_in[0];
  const float* feat_B = (const float*)d_in[1];
  // d_in[2] = H_mat : unused by the reference computation
  const float* vmask  = (const float*)d_in[3];

  unsigned short* fAn = (unsigned short*)d_ws;            // 4 MB bf16 fragment-major
  unsigned short* fBn = fAn + (size_t)BB * HW * CC;       // 4 MB
  float* diag   = (float*)(fBn + (size_t)BB * HW * CC);   // 64 KB
  float* expsum = diag + BB * HW;                         // 64 KB
  float* acc    = expsum + BB * HW;                       // num, den, counter
  float* out    = (float*)d_out;

  k_prep<<<512,  256, 0, stream>>>(feat_A, feat_B, fAn, fBn, diag, expsum, acc);
  k_main<<<4096, 256, 0, stream>>>(fAn, fBn, expsum, diag, vmask, acc, out);
}